// Round 4
// baseline (278.860 us; speedup 1.0000x reference)
//
#include <hip/hip_runtime.h>

// ChannelBlockImportanceGate: B=8, C=256, H=W=132, BLOCK=8, KEEP_RATIO=0.25
// Output = hard top-72 block mask (of 289 blocks) upsampled 8x, per (b,c) plane.
// Straight-through soft blend cancels numerically -> output is the hard mask.
//
// v4: SPLIT kernel. A = coalesced float4 stream + f64 LDS atomics (verified
// v2b) + u32-key stable rank (verified v3) -> u8 mask per block to workspace.
// B = pure upsample/write kernel (LDS mask broadcast + NT float4 stores) that
// saturates the write pipe with no phase convoy. Monolithic fallback if the
// workspace is too small.

#define HH 132
#define WW 132
#define NB 17          // blocks per side (ceil(132/8) = 17)
#define TOTAL 289      // NB*NB
#define NPAD 320       // padded key/score count (multiple of 64)
#define KEEP 72        // round(289*0.25)
#define NV ((HH * WW) / 4)   // 4356 float4s per plane (132%4==0)
#define PLANES 2048

typedef float floatx4 __attribute__((ext_vector_type(4)));

// ---------------- Kernel A: block scores + top-72 mask ----------------
__global__ __launch_bounds__(NPAD)
void gate_score(const float4* __restrict__ feats4,
                const int* __restrict__ enabled_p,
                unsigned char* __restrict__ ws_mask) {
    const int plane = blockIdx.x;
    const int t = threadIdx.x;               // 0..319
    const float4* __restrict__ fp = feats4 + (size_t)plane * NV;

    __shared__ __align__(16) double   s_score[NPAD];
    __shared__ __align__(16) unsigned s_key[NPAD];

    s_score[t] = 0.0;                        // pad entries stay 0 -> key 0
    __syncthreads();

    // Coalesced float4 stream; each float4 maps to exactly one block
    // (132 % 4 == 0). fp64 atomic accumulation: ordering noise ~1e-15 rel,
    // cannot perturb ranking.
    for (int v = t; v < NV; v += NPAD) {
        const float4 x = fp[v];
        const double s = (double)fabsf(x.x) + (double)fabsf(x.y)
                       + (double)fabsf(x.z) + (double)fabsf(x.w);
        const int base = v * 4;
        const int row = base / WW;           // magic-mul division
        const int col = base - row * WW;
        atomicAdd(&s_score[(row >> 3) * NB + (col >> 3)], s);  // ds_add_f64
    }
    __syncthreads();

    // Sortable u32 keys: sums >= 0 -> hi32 bits of f64 are order-monotone.
    s_key[t] = (unsigned)((unsigned long long)
                   __double_as_longlong(s_score[t]) >> 32);
    __syncthreads();

    // Stable rank (matches lax.top_k tie order), u32 fast path with exact
    // f64 fallback on key ties (e > 1). 289 items <= 320 threads: one pass.
    const int en = *enabled_p;
    if (t < TOTAL) {
        const unsigned ki = s_key[t];
        const uint4* __restrict__ sk4 = (const uint4*)s_key;
        int r = 0, e = 0;
        #pragma unroll 10
        for (int q = 0; q < NPAD / 4; ++q) {    // 80 uint4 broadcast reads
            const uint4 k = sk4[q];
            r += (int)(k.x > ki) + (int)(k.y > ki)
               + (int)(k.z > ki) + (int)(k.w > ki);
            e += (int)(k.x == ki) + (int)(k.y == ki)
               + (int)(k.z == ki) + (int)(k.w == ki);
        }
        int rank = r;                            // e==1: only self equals
        if (e > 1) {
            const double si = s_score[t];
            rank = 0;
            for (int j = 0; j < TOTAL; ++j) {
                const double sj = s_score[j];
                rank += (int)((sj > si) || ((sj == si) && (j < t)));
            }
        }
        ws_mask[(size_t)plane * TOTAL + t] =
            (unsigned char)((!en || rank < KEEP) ? 1 : 0);
    }
}

// ---------------- Kernel B: upsample 8x, pure write stream ----------------
#define NTB 256
__global__ __launch_bounds__(NTB)
void gate_write(const unsigned char* __restrict__ ws_mask,
                float4* __restrict__ out4) {
    const int plane = blockIdx.x;
    const int t = threadIdx.x;
    floatx4* __restrict__ op = (floatx4*)(out4 + (size_t)plane * NV);

    __shared__ float s_hard[TOTAL];
    const unsigned char* __restrict__ mp = ws_mask + (size_t)plane * TOTAL;
    for (int i = t; i < TOTAL; i += NTB) s_hard[i] = (float)mp[i];
    __syncthreads();

    for (int v = t; v < NV; v += NTB) {
        const int base = v * 4;
        const int row = base / WW;              // magic-mul division
        const int col = base - row * WW;
        const float m = s_hard[(row >> 3) * NB + (col >> 3)];
        const floatx4 mv = {m, m, m, m};
        __builtin_nontemporal_store(mv, &op[v]);
    }
}

// ---------------- Fallback: monolithic v2b (ws too small) ----------------
__global__ __launch_bounds__(NTB)
void gate_mono(const float4* __restrict__ feats4,
               const int* __restrict__ enabled_p,
               float4* __restrict__ out4) {
    const int plane = blockIdx.x;
    const int t = threadIdx.x;
    const float4* __restrict__ fp = feats4 + (size_t)plane * NV;
    floatx4* __restrict__ op = (floatx4*)(out4 + (size_t)plane * NV);

    __shared__ __align__(16) double   s_score[NPAD];
    __shared__ __align__(16) unsigned s_key[NPAD];
    __shared__ float s_hard[TOTAL];

    for (int i = t; i < NPAD; i += NTB) s_score[i] = 0.0;
    __syncthreads();
    for (int v = t; v < NV; v += NTB) {
        const float4 x = fp[v];
        const double s = (double)fabsf(x.x) + (double)fabsf(x.y)
                       + (double)fabsf(x.z) + (double)fabsf(x.w);
        const int base = v * 4;
        const int row = base / WW;
        const int col = base - row * WW;
        atomicAdd(&s_score[(row >> 3) * NB + (col >> 3)], s);
    }
    __syncthreads();
    for (int i = t; i < NPAD; i += NTB)
        s_key[i] = (unsigned)((unsigned long long)
                       __double_as_longlong(s_score[i]) >> 32);
    __syncthreads();
    const int en = *enabled_p;
    const uint4* __restrict__ sk4 = (const uint4*)s_key;
    for (int i = t; i < TOTAL; i += NTB) {
        const unsigned ki = s_key[i];
        int r = 0, e = 0;
        #pragma unroll 10
        for (int q = 0; q < NPAD / 4; ++q) {
            const uint4 k = sk4[q];
            r += (int)(k.x > ki) + (int)(k.y > ki)
               + (int)(k.z > ki) + (int)(k.w > ki);
            e += (int)(k.x == ki) + (int)(k.y == ki)
               + (int)(k.z == ki) + (int)(k.w == ki);
        }
        int rank = r;
        if (e > 1) {
            const double si = s_score[i];
            rank = 0;
            for (int j = 0; j < TOTAL; ++j) {
                const double sj = s_score[j];
                rank += (int)((sj > si) || ((sj == si) && (j < i)));
            }
        }
        s_hard[i] = (!en || rank < KEEP) ? 1.0f : 0.0f;
    }
    __syncthreads();
    for (int v = t; v < NV; v += NTB) {
        const int base = v * 4;
        const int row = base / WW;
        const int col = base - row * WW;
        const float m = s_hard[(row >> 3) * NB + (col >> 3)];
        const floatx4 mv = {m, m, m, m};
        __builtin_nontemporal_store(mv, &op[v]);
    }
}

extern "C" void kernel_launch(void* const* d_in, const int* in_sizes, int n_in,
                              void* d_out, int out_size, void* d_ws, size_t ws_size,
                              hipStream_t stream) {
    const float4* feats = (const float4*)d_in[0];
    const int* enabled = (const int*)d_in[1];
    float4* out = (float4*)d_out;
    const size_t need = (size_t)PLANES * TOTAL;      // 592 KB of u8 masks
    if (d_ws != nullptr && ws_size >= need) {
        unsigned char* mask = (unsigned char*)d_ws;
        gate_score<<<PLANES, NPAD, 0, stream>>>(feats, enabled, mask);
        gate_write<<<PLANES, NTB, 0, stream>>>(mask, out);
    } else {
        gate_mono<<<PLANES, NTB, 0, stream>>>(feats, enabled, out);
    }
}

// Round 5
// 277.900 us; speedup vs baseline: 1.0035x; 1.0035x over previous
//
#include <hip/hip_runtime.h>

// ChannelBlockImportanceGate: B=8, C=256, H=W=132, BLOCK=8, KEEP_RATIO=0.25
// Output = hard top-72 block mask (of 289 blocks) upsampled 8x, per (b,c) plane.
// Straight-through soft blend cancels numerically -> output is the hard mask.
//
// v5: monolith (cross-block overlap pipelines read/write phases for free —
// proven by v4 split: score alone was 87us, monolith incl. writes 94.7us).
// Scoring is ATOMIC-FREE: v4's gate_score ran at 830 GB/s because wave-wide
// ds_add_f64 with duplicate addresses serializes per-lane RMW (~50us of LDS
// pipe). Replaced with a 2-stage non-atomic LDS reduction:
//   stage 1: 561 items = 17 block-rows x 33 float4-cols, vertical 8-row f64
//            sum per float4-col, coalesced loads, plain LDS writes;
//   stage 2: 289 block scores = 2 col-entries each + sortable-u32 keys.
// Rank: u32-key stable rank w/ exact f64 fallback on key ties (verified v3).
// Write: NT float4 stores (verified v2b).

#define HH 132
#define WW 132
#define NB 17            // blocks per side
#define TOTAL 289        // NB*NB
#define NPAD 320         // padded keys (multiple of 64)
#define KEEP 72          // round(289*0.25)
#define NTH 256
#define NC4 33           // float4s per row (132/4)
#define NCOL (17 * 33)   // 561 stage-1 items
#define NV ((HH * WW) / 4)   // 4356 float4s per plane
#define PLANES 2048

typedef float floatx4 __attribute__((ext_vector_type(4)));

__global__ __launch_bounds__(NTH)
void gate_kernel(const float4* __restrict__ feats4,
                 const int* __restrict__ enabled_p,
                 float4* __restrict__ out4) {
    const int plane = blockIdx.x;
    const int t = threadIdx.x;
    const float4* __restrict__ fp = feats4 + (size_t)plane * NV;
    floatx4* __restrict__ op = (floatx4*)(out4 + (size_t)plane * NV);

    __shared__ __align__(16) double   s_col[NCOL];    // [br][c4]
    __shared__ __align__(16) double   s_score[NPAD];
    __shared__ __align__(16) unsigned s_key[NPAD];
    __shared__ float s_hard[TOTAL];

    // ---- Stage 1: vertical 8-row |x| sums per float4-column, f64, no atomics
    for (int w = t; w < NCOL; w += NTH) {
        const int br = w / NC4;              // block-row 0..16
        const int c4 = w - br * NC4;         // float4-col 0..32
        const int nr = (br == NB - 1) ? 4 : 8;   // bottom stripe has 4 rows
        const float4* cp = fp + br * (8 * NC4) + c4;
        double acc = 0.0;
        #pragma unroll
        for (int k = 0; k < 8; ++k) {
            if (k < nr) {                    // predicated; no OOB on last plane
                const float4 x = cp[k * NC4];
                acc += (double)fabsf(x.x) + (double)fabsf(x.y)
                     + (double)fabsf(x.z) + (double)fabsf(x.w);
            }
        }
        s_col[w] = acc;
    }
    __syncthreads();

    // ---- Stage 2: block scores (2 col-entries, right edge 1) + u32 keys ----
    // sums >= 0 -> hi32 of f64 bits is order-monotone (unsigned).
    for (int b = t; b < NPAD; b += NTH) {
        double s = 0.0;
        if (b < TOTAL) {
            const int br = b / NB;
            const int bc = b - br * NB;
            const double* rp = &s_col[br * NC4 + 2 * bc];
            s = (bc == NB - 1) ? rp[0] : (rp[0] + rp[1]);
        }
        s_score[b] = s;
        s_key[b] = (unsigned)((unsigned long long)__double_as_longlong(s) >> 32);
    }
    __syncthreads();

    // ---- Rank: stable top-72 (matches lax.top_k ties), u32 fast path ----
    const int en = *enabled_p;
    const uint4* __restrict__ sk4 = (const uint4*)s_key;
    for (int i = t; i < TOTAL; i += NTH) {
        const unsigned ki = s_key[i];
        int r = 0, e = 0;
        #pragma unroll 10
        for (int q = 0; q < NPAD / 4; ++q) {     // 80 uint4 broadcast reads
            const uint4 k = sk4[q];
            r += (int)(k.x > ki) + (int)(k.y > ki)
               + (int)(k.z > ki) + (int)(k.w > ki);
            e += (int)(k.x == ki) + (int)(k.y == ki)
               + (int)(k.z == ki) + (int)(k.w == ki);
        }
        int rank = r;                            // e==1: only self equals
        if (e > 1) {                             // key tie -> exact f64 rank
            const double si = s_score[i];
            rank = 0;
            for (int j = 0; j < TOTAL; ++j) {
                const double sj = s_score[j];
                rank += (int)((sj > si) || ((sj == si) && (j < i)));
            }
        }
        s_hard[i] = (!en || rank < KEEP) ? 1.0f : 0.0f;
    }
    __syncthreads();

    // ---- Upsample 8x, nontemporal float4 stores ----
    for (int v = t; v < NV; v += NTH) {
        const int base = v * 4;
        const int row = base / WW;               // magic-mul division
        const int col = base - row * WW;
        const float m = s_hard[(row >> 3) * NB + (col >> 3)];
        const floatx4 mv = {m, m, m, m};
        __builtin_nontemporal_store(mv, &op[v]);
    }
}

extern "C" void kernel_launch(void* const* d_in, const int* in_sizes, int n_in,
                              void* d_out, int out_size, void* d_ws, size_t ws_size,
                              hipStream_t stream) {
    const float4* feats = (const float4*)d_in[0];
    const int* enabled = (const int*)d_in[1];
    float4* out = (float4*)d_out;
    gate_kernel<<<PLANES, NTH, 0, stream>>>(feats, enabled, out);
}

// Round 6
// 273.152 us; speedup vs baseline: 1.0209x; 1.0174x over previous
//
#include <hip/hip_runtime.h>

// ChannelBlockImportanceGate: B=8, C=256, H=W=132, BLOCK=8, KEEP_RATIO=0.25
// Output = hard top-72 block mask (of 289 blocks) upsampled 8x, per (b,c) plane.
// Straight-through soft blend cancels numerically -> output is the hard mask.
//
// v6: 2-kernel split, both shaped like measured-fast kernels:
//  A gate_score (8192 blocks, 4/plane, 4-5 stripes each): contiguous coalesced
//    float4 stream -> per-element f64 LDS cells (no atomics) -> 1 barrier ->
//    small reduce -> 289 sortable u64 keys/plane to ws (5.2 MB).
//  B gate_write (2048 blocks): load keys -> u32-hi fast rank (u64-exact
//    fallback on hi-key ties) -> 17 NT float4 stores/thread (v4's ~27us
//    write kernel + cheap rank preamble).
//  Evidence: fillBuffer hits 6.6 TB/s; v4 gate_write ~27us; monolith stuck
//  ~100us regardless of structure (phase convoy). Monolith fallback if ws
//  too small.

#define HH 132
#define WW 132
#define NB 17            // blocks per side
#define TOTAL 289        // NB*NB
#define NPAD 320         // padded keys (multiple of 64)
#define KEEP 72          // round(289*0.25)
#define NTH 256
#define NC4 33           // float4s per row (132/4)
#define SF4 264          // float4s per 8-row stripe (8*33)
#define NV ((HH * WW) / 4)   // 4356 float4s per plane
#define PLANES 2048

typedef float floatx4 __attribute__((ext_vector_type(4)));

// ---------------- Kernel A: stripe-group scores -> u64 keys ----------------
__global__ __launch_bounds__(NTH)
void gate_score(const float4* __restrict__ feats4,
                unsigned long long* __restrict__ ws_key) {
    const int gid = blockIdx.x;              // 0..8191
    const int plane = gid >> 2;
    const int g = gid & 3;                   // stripe group: 4,4,4,5 stripes
    const int sg0 = g * 4;
    const int ns = (g == 3) ? 5 : 4;
    const int t = threadIdx.x;
    const float4* __restrict__ fp = feats4 + (size_t)plane * NV;

    __shared__ __align__(16) double s_e[5 * SF4];    // 10560 B

    // Contiguous coalesced stream: stripe s occupies float4s
    // [(sg0+s)*264, +264). Plane-end guard zeroes the 4 pad rows of the
    // last stripe (g==3, s==4: gi >= 4356).
    for (int s = 0; s < ns; ++s) {
        const int base = (sg0 + s) * SF4;
        for (int v = t; v < SF4; v += NTH) {
            const int gi = base + v;
            double acc = 0.0;
            if (gi < NV) {
                const float4 x = fp[gi];
                acc = (double)fabsf(x.x) + (double)fabsf(x.y)
                    + (double)fabsf(x.z) + (double)fabsf(x.w);
            }
            s_e[s * SF4 + v] = acc;
        }
    }
    __syncthreads();

    // Reduce 16 cells (8 rows x 2 float4-cols; right edge 8 x 1) per block
    // score; write sortable u64 key (f64 bits of non-negative sum are
    // order-monotone as unsigned).
    const int nsc = ns * NB;                 // 68 or 85 scores
    for (int j = t; j < nsc; j += NTH) {
        const int sl = j / NB;               // stripe within group
        const int i = j - sl * NB;           // block col 0..16
        const double* ep = &s_e[sl * SF4];
        double sum = 0.0;
        if (i < 16) {
            #pragma unroll
            for (int r = 0; r < 8; ++r)
                sum += ep[r * NC4 + 2 * i] + ep[r * NC4 + 2 * i + 1];
        } else {
            #pragma unroll
            for (int r = 0; r < 8; ++r)
                sum += ep[r * NC4 + 32];
        }
        ws_key[(size_t)plane * NPAD + (sg0 + sl) * NB + i] =
            (unsigned long long)__double_as_longlong(sum);
    }
}

// ---------------- Kernel B: rank + upsample write ----------------
__global__ __launch_bounds__(NTH)
void gate_write(const unsigned long long* __restrict__ ws_key,
                const int* __restrict__ enabled_p,
                float4* __restrict__ out4) {
    const int plane = blockIdx.x;
    const int t = threadIdx.x;

    __shared__ __align__(16) unsigned long long s_k64[NPAD];
    __shared__ __align__(16) unsigned s_key[NPAD];
    __shared__ float s_hard[TOTAL];

    const unsigned long long* __restrict__ kp = ws_key + (size_t)plane * NPAD;
    for (int i = t; i < NPAD; i += NTH) {
        const unsigned long long k = (i < TOTAL) ? kp[i] : 0ULL;
        s_k64[i] = k;
        s_key[i] = (unsigned)(k >> 32);
    }
    __syncthreads();

    // Stable top-72 rank (matches lax.top_k ties): u32-hi fast path,
    // exact u64 fallback when hi-keys tie (e > 1). Pads have key 0.
    const int en = *enabled_p;
    const uint4* __restrict__ sk4 = (const uint4*)s_key;
    for (int i = t; i < TOTAL; i += NTH) {
        const unsigned ki = s_key[i];
        int r = 0, e = 0;
        #pragma unroll 10
        for (int q = 0; q < NPAD / 4; ++q) {     // 80 uint4 broadcast reads
            const uint4 k = sk4[q];
            r += (int)(k.x > ki) + (int)(k.y > ki)
               + (int)(k.z > ki) + (int)(k.w > ki);
            e += (int)(k.x == ki) + (int)(k.y == ki)
               + (int)(k.z == ki) + (int)(k.w == ki);
        }
        int rank = r;
        if (e > 1) {
            const unsigned long long ki64 = s_k64[i];
            rank = 0;
            for (int j = 0; j < TOTAL; ++j) {
                const unsigned long long kj = s_k64[j];
                rank += (int)((kj > ki64) || ((kj == ki64) && (j < i)));
            }
        }
        s_hard[i] = (!en || rank < KEEP) ? 1.0f : 0.0f;
    }
    __syncthreads();

    // Pure write stream: 17 NT float4 stores per thread.
    floatx4* __restrict__ op = (floatx4*)(out4 + (size_t)plane * NV);
    for (int v = t; v < NV; v += NTH) {
        const int base = v * 4;
        const int row = base / WW;               // magic-mul division
        const int col = base - row * WW;
        const float m = s_hard[(row >> 3) * NB + (col >> 3)];
        const floatx4 mv = {m, m, m, m};
        __builtin_nontemporal_store(mv, &op[v]);
    }
}

// ---------------- Fallback: monolithic v2b (ws too small) ----------------
__global__ __launch_bounds__(NTH)
void gate_mono(const float4* __restrict__ feats4,
               const int* __restrict__ enabled_p,
               float4* __restrict__ out4) {
    const int plane = blockIdx.x;
    const int t = threadIdx.x;
    const float4* __restrict__ fp = feats4 + (size_t)plane * NV;
    floatx4* __restrict__ op = (floatx4*)(out4 + (size_t)plane * NV);

    __shared__ __align__(16) double   s_score[NPAD];
    __shared__ __align__(16) unsigned s_key[NPAD];
    __shared__ float s_hard[TOTAL];

    for (int i = t; i < NPAD; i += NTH) s_score[i] = 0.0;
    __syncthreads();
    for (int v = t; v < NV; v += NTH) {
        const float4 x = fp[v];
        const double s = (double)fabsf(x.x) + (double)fabsf(x.y)
                       + (double)fabsf(x.z) + (double)fabsf(x.w);
        const int base = v * 4;
        const int row = base / WW;
        const int col = base - row * WW;
        atomicAdd(&s_score[(row >> 3) * NB + (col >> 3)], s);
    }
    __syncthreads();
    for (int i = t; i < NPAD; i += NTH)
        s_key[i] = (unsigned)((unsigned long long)
                       __double_as_longlong(s_score[i]) >> 32);
    __syncthreads();
    const int en = *enabled_p;
    const uint4* __restrict__ sk4 = (const uint4*)s_key;
    for (int i = t; i < TOTAL; i += NTH) {
        const unsigned ki = s_key[i];
        int r = 0, e = 0;
        #pragma unroll 10
        for (int q = 0; q < NPAD / 4; ++q) {
            const uint4 k = sk4[q];
            r += (int)(k.x > ki) + (int)(k.y > ki)
               + (int)(k.z > ki) + (int)(k.w > ki);
            e += (int)(k.x == ki) + (int)(k.y == ki)
               + (int)(k.z == ki) + (int)(k.w == ki);
        }
        int rank = r;
        if (e > 1) {
            const double si = s_score[i];
            rank = 0;
            for (int j = 0; j < TOTAL; ++j) {
                const double sj = s_score[j];
                rank += (int)((sj > si) || ((sj == si) && (j < i)));
            }
        }
        s_hard[i] = (!en || rank < KEEP) ? 1.0f : 0.0f;
    }
    __syncthreads();
    for (int v = t; v < NV; v += NTH) {
        const int base = v * 4;
        const int row = base / WW;
        const int col = base - row * WW;
        const float m = s_hard[(row >> 3) * NB + (col >> 3)];
        const floatx4 mv = {m, m, m, m};
        __builtin_nontemporal_store(mv, &op[v]);
    }
}

extern "C" void kernel_launch(void* const* d_in, const int* in_sizes, int n_in,
                              void* d_out, int out_size, void* d_ws, size_t ws_size,
                              hipStream_t stream) {
    const float4* feats = (const float4*)d_in[0];
    const int* enabled = (const int*)d_in[1];
    float4* out = (float4*)d_out;
    const size_t need = (size_t)PLANES * NPAD * sizeof(unsigned long long);
    if (d_ws != nullptr && ws_size >= need) {
        unsigned long long* wkey = (unsigned long long*)d_ws;
        gate_score<<<PLANES * 4, NTH, 0, stream>>>(feats, wkey);
        gate_write<<<PLANES, NTH, 0, stream>>>(wkey, enabled, out);
    } else {
        gate_mono<<<PLANES, NTH, 0, stream>>>(feats, enabled, out);
    }
}

// Round 8
// 268.464 us; speedup vs baseline: 1.0387x; 1.0175x over previous
//
#include <hip/hip_runtime.h>

// ChannelBlockImportanceGate: B=8, C=256, H=W=132, BLOCK=8, KEEP_RATIO=0.25
// Output = hard top-72 block mask (of 289 blocks) upsampled 8x, per (b,c) plane.
// Straight-through soft blend cancels numerically -> output is the hard mask.
//
// v8 = v7 (whole-plane async LDS staging) + right-edge fix: block col 16 is
// only 4 px wide (17*8=136>132); v7 read 8 px there, poisoning the ranking.
//
// Latency theory (v7): all prior read phases kept ~1 load in flight per wave
// (register load -> dependent LDS op -> vmcnt wait) so reads ran ~2 TB/s
// regardless of structure. Fix: __builtin_amdgcn_global_load_lds fire-and-
// forget DMA, 17x1KB per wave in flight, one drain at the barrier (m93->m97
// mechanism). Then thread-per-block 8x8 reduce from LDS, verified u32-key
// stable rank, verified NT-store upsample.

#define HH 132
#define WW 132
#define NB 17            // blocks per side
#define TOTAL 289        // NB*NB
#define NPAD 320         // padded keys (multiple of 64)
#define KEEP 72          // round(289*0.25)
#define NTH 256
#define NV 4356          // float4s per plane (132*132/4)
#define NCHUNK 68        // full 64-float4 (1KB) DMA chunks = 4352 float4s
#define PLANES 2048

typedef float floatx4 __attribute__((ext_vector_type(4)));
typedef const __attribute__((address_space(1))) void* gas_p;
typedef __attribute__((address_space(3))) void* las_p;

__global__ __launch_bounds__(NTH)
void gate_kernel(const float4* __restrict__ feats4,
                 const int* __restrict__ enabled_p,
                 float4* __restrict__ out4) {
    const int plane = blockIdx.x;
    const int t = threadIdx.x;
    const int wid = t >> 6;
    const int lane = t & 63;
    const float4* __restrict__ fp = feats4 + (size_t)plane * NV;

    __shared__ __align__(16) float4   s_plane[NV];     // 69696 B
    __shared__ __align__(16) double   s_score[NPAD];
    __shared__ __align__(16) unsigned s_key[NPAD];
    __shared__ float s_hard[TOTAL];
    // total ~74.7 KB -> 2 blocks/CU (low occupancy is intentional)

    // ---- Stage: async global->LDS. Wave w issues 17 independent 1KB DMAs
    // (chunks w*17..w*17+16); LDS dest is wave-uniform base + lane*16,
    // global src is per-lane. No register landing, no waits until barrier.
    {
        const int c0 = wid * 17;
        #pragma unroll
        for (int k = 0; k < 17; ++k) {
            const int chunk = c0 + k;
            __builtin_amdgcn_global_load_lds(
                (gas_p)(fp + (chunk * 64 + lane)),
                (las_p)(s_plane + chunk * 64),
                16, 0, 0);
        }
    }
    if (t < NV - NCHUNK * 64)                 // 4 tail float4s (4352..4355)
        s_plane[NCHUNK * 64 + t] = fp[NCHUNK * 64 + t];
    __syncthreads();                          // drains vmcnt + lgkmcnt

    // ---- Score: thread-per-block 8x8 |x| sums from LDS, f64-exact.
    // Right-edge blocks (bc==16) are 4 px wide: ONE float4 only.
    // Row order rotated by (t&7) to de-alias the 32B lane stride.
    const float* __restrict__ sp = (const float*)s_plane;
    for (int b = t; b < NPAD; b += NTH) {
        double sum = 0.0;
        if (b < TOTAL) {
            const int br = b / NB;
            const int bc = b - br * NB;
            const int nr = (br == NB - 1) ? 4 : 8;   // bottom stripe: 4 rows
            const int two = (bc < NB - 1);           // right edge: 1 float4
            const int rot = t & 7;
            #pragma unroll
            for (int rr = 0; rr < 8; ++rr) {
                const int r = (rr + rot) & 7;
                if (r < nr) {
                    const float* rp = sp + (br * 8 + r) * WW + bc * 8;
                    const floatx4 a = *(const floatx4*)rp;
                    sum += (double)fabsf(a.x) + (double)fabsf(a.y)
                         + (double)fabsf(a.z) + (double)fabsf(a.w);
                    if (two) {
                        const floatx4 c = *(const floatx4*)(rp + 4);
                        sum += (double)fabsf(c.x) + (double)fabsf(c.y)
                             + (double)fabsf(c.z) + (double)fabsf(c.w);
                    }
                }
            }
        }
        s_score[b] = sum;                     // pads (289..319) stay 0
        s_key[b] = (unsigned)((unsigned long long)
                       __double_as_longlong(sum) >> 32);
    }
    __syncthreads();

    // ---- Rank: stable top-72 (matches lax.top_k ties), u32 fast path,
    // exact f64 fallback on key ties (e > 1). Verified v3/v5/v6.
    const int en = *enabled_p;
    const uint4* __restrict__ sk4 = (const uint4*)s_key;
    for (int i = t; i < TOTAL; i += NTH) {
        const unsigned ki = s_key[i];
        int r = 0, e = 0;
        #pragma unroll 10
        for (int q = 0; q < NPAD / 4; ++q) {  // 80 uint4 broadcast reads
            const uint4 k = sk4[q];
            r += (int)(k.x > ki) + (int)(k.y > ki)
               + (int)(k.z > ki) + (int)(k.w > ki);
            e += (int)(k.x == ki) + (int)(k.y == ki)
               + (int)(k.z == ki) + (int)(k.w == ki);
        }
        int rank = r;                         // e==1: only self equals
        if (e > 1) {
            const double si = s_score[i];
            rank = 0;
            for (int j = 0; j < TOTAL; ++j) {
                const double sj = s_score[j];
                rank += (int)((sj > si) || ((sj == si) && (j < i)));
            }
        }
        s_hard[i] = (!en || rank < KEEP) ? 1.0f : 0.0f;
    }
    __syncthreads();

    // ---- Upsample 8x, nontemporal float4 stores (verified). ----
    floatx4* __restrict__ op = (floatx4*)(out4 + (size_t)plane * NV);
    for (int v = t; v < NV; v += NTH) {
        const int base = v * 4;
        const int row = base / WW;            // magic-mul division
        const int col = base - row * WW;
        const float m = s_hard[(row >> 3) * NB + (col >> 3)];
        const floatx4 mv = {m, m, m, m};
        __builtin_nontemporal_store(mv, &op[v]);
    }
}

extern "C" void kernel_launch(void* const* d_in, const int* in_sizes, int n_in,
                              void* d_out, int out_size, void* d_ws, size_t ws_size,
                              hipStream_t stream) {
    const float4* feats = (const float4*)d_in[0];
    const int* enabled = (const int*)d_in[1];
    float4* out = (float4*)d_out;
    gate_kernel<<<PLANES, NTH, 0, stream>>>(feats, enabled, out);
}

// Round 9
// 256.168 us; speedup vs baseline: 1.0886x; 1.0480x over previous
//
#include <hip/hip_runtime.h>

// ChannelBlockImportanceGate: B=8, C=256, H=W=132, BLOCK=8, KEEP_RATIO=0.25
// Output = hard top-72 block mask (of 289 blocks) upsampled 8x, per (b,c) plane.
// Straight-through soft blend cancels numerically -> output is the hard mask.
//
// v9: kill the f64 hot path (every prior variant: cvt+add_f64 on all 17424
// elements ~25us/CU) and the f64 rank fallback. Sum-of-phases model fits all
// 8 measured variants (87-120us). New structure, all phases minimal:
//  A: coalesced grid-stride float4 loads -> per-float4 f32 |sum| -> plain LDS
//     bin s_e[v] (conflict-free, deterministic, no atomics).
//  B: per-block 16-bin reduce in f64 (289x16 ops only); key = f32 bit pattern
//     (monotone for non-negative floats).
//  C: stable top-72 rank, pure-u32 fused tie-break (matches lax.top_k index
//     order on exact f32 ties; no fallback loop).
//  D: NT float4 upsample stores (verified).
// LDS 19.7KB -> 8 blocks/CU, whole grid co-resident; phases overlap across
// blocks.

#define HH 132
#define WW 132
#define NB 17            // blocks per side
#define TOTAL 289        // NB*NB
#define NKPAD 292        // keys padded to multiple of 4
#define KEEP 72          // round(289*0.25)
#define NTH 256
#define NC4 33           // float4s per row (132/4)
#define NV 4356          // float4s per plane
#define PLANES 2048

typedef float floatx4 __attribute__((ext_vector_type(4)));

__global__ __launch_bounds__(NTH)
void gate_kernel(const float4* __restrict__ feats4,
                 const int* __restrict__ enabled_p,
                 float4* __restrict__ out4) {
    const int plane = blockIdx.x;
    const int t = threadIdx.x;
    const float4* __restrict__ fp = feats4 + (size_t)plane * NV;

    __shared__ __align__(16) float    s_e[NV];       // 17424 B
    __shared__ __align__(16) unsigned s_key[NKPAD];  // 1168 B
    __shared__ float s_hard[TOTAL];                  // 1156 B
    // total 19748 B -> 8 blocks/CU

    // ---- Phase A: coalesced stream, per-float4 f32 |sum| -> LDS bin ----
    // v = row*33 + c4 directly indexes s_e; zero addressing math.
    #pragma unroll
    for (int k = 0; k < 18; ++k) {
        const int v = t + k * NTH;                   // 18*256 covers 4356
        if (v < NV) {
            const float4 x = fp[v];
            s_e[v] = (fabsf(x.x) + fabsf(x.y)) + (fabsf(x.z) + fabsf(x.w));
        }
    }
    __syncthreads();

    // ---- Phase B: block scores. 16 bins (8 rows x 2 float4-cols; right
    // edge 8x1), reduced in f64 (cheap: 289x16 ops) for near-exact order.
    // Key = f32 bits of the score: order-monotone as unsigned (score >= 0).
    for (int b = t; b < TOTAL; b += NTH) {
        const int br = b / NB;                       // magic-mul
        const int bc = b - br * NB;
        const int nr = (br == NB - 1) ? 4 : 8;       // bottom stripe: 4 rows
        const int base = (br * 8) * NC4 + 2 * bc;    // bc==16 -> c4=32 (edge)
        double sum = 0.0;
        if (bc < NB - 1) {
            for (int rr = 0; rr < nr; ++rr)
                sum += (double)s_e[base + rr * NC4]
                     + (double)s_e[base + rr * NC4 + 1];
        } else {
            for (int rr = 0; rr < nr; ++rr)
                sum += (double)s_e[base + rr * NC4];
        }
        s_key[b] = __float_as_uint((float)sum);
    }
    if (t < NKPAD - TOTAL) s_key[TOTAL + t] = 0u;    // pad keys
    __syncthreads();

    // ---- Phase C: stable top-72 rank (lax.top_k tie order), pure u32.
    // contribution(j) = (kj > ki) || (kj == ki && j < i); j = 4q + c,
    // (j < i) <=> (q < thr_c) with thr_c = floor((i - c + 3) / 4).
    const int en = *enabled_p;
    for (int i = t; i < TOTAL; i += NTH) {
        const unsigned ki = s_key[i];
        const int thr0 = (i + 3) >> 2;
        const int thr1 = (i + 2) >> 2;
        const int thr2 = (i + 1) >> 2;
        const int thr3 =  i      >> 2;
        const uint4* __restrict__ sk4 = (const uint4*)s_key;
        int rank = 0;
        #pragma unroll 8
        for (int q = 0; q < NKPAD / 4; ++q) {        // 73 uint4 broadcast reads
            const uint4 k = sk4[q];
            rank += (int)((k.x > ki) || ((k.x == ki) && (q < thr0)));
            rank += (int)((k.y > ki) || ((k.y == ki) && (q < thr1)));
            rank += (int)((k.z > ki) || ((k.z == ki) && (q < thr2)));
            rank += (int)((k.w > ki) || ((k.w == ki) && (q < thr3)));
        }
        s_hard[i] = (!en || rank < KEEP) ? 1.0f : 0.0f;
    }
    __syncthreads();

    // ---- Phase D: upsample 8x, nontemporal float4 stores (verified) ----
    floatx4* __restrict__ op = (floatx4*)(out4 + (size_t)plane * NV);
    for (int v = t; v < NV; v += NTH) {
        const int base = v * 4;
        const int row = base / WW;                   // magic-mul
        const int col = base - row * WW;
        const float m = s_hard[(row >> 3) * NB + (col >> 3)];
        const floatx4 mv = {m, m, m, m};
        __builtin_nontemporal_store(mv, &op[v]);
    }
}

extern "C" void kernel_launch(void* const* d_in, const int* in_sizes, int n_in,
                              void* d_out, int out_size, void* d_ws, size_t ws_size,
                              hipStream_t stream) {
    const float4* feats = (const float4*)d_in[0];
    const int* enabled = (const int*)d_in[1];
    float4* out = (float4*)d_out;
    gate_kernel<<<PLANES, NTH, 0, stream>>>(feats, enabled, out);
}